// Round 8
// baseline (648.556 us; speedup 1.0000x reference)
//
#include <hip/hip_runtime.h>
#include <hip/hip_bf16.h>

#define N_COARSE 12500
#define N_FINE   50000

typedef __bf16 bf16x8 __attribute__((ext_vector_type(8)));
typedef __bf16 bf16x4 __attribute__((ext_vector_type(4)));
typedef float  f32x4  __attribute__((ext_vector_type(4)));

// ---------------------------------------------------------------------------
// Fragment conventions (v_mfma_f32_16x16x32_bf16), HW-verified:
//   a-frag: lane holds A[row = lane&15][k = (lane>>4)*8 + j]
//   b-frag: lane holds B[k = (lane>>4)*8 + j][col = lane&15]
//   d     : lane holds D[row = (lane>>4)*4 + j][col = lane&15]
// ---------------------------------------------------------------------------

__device__ __forceinline__ bf16x8 cvt8(f32x4 x, f32x4 y) {
    bf16x8 r;
    r[0] = (__bf16)x[0]; r[1] = (__bf16)x[1]; r[2] = (__bf16)x[2]; r[3] = (__bf16)x[3];
    r[4] = (__bf16)y[0]; r[5] = (__bf16)y[1]; r[6] = (__bf16)y[2]; r[7] = (__bf16)y[3];
    return r;
}

// Barrier with LDS-only fence (k_out only; avoids __syncthreads' vmcnt drain)
__device__ __forceinline__ void lds_barrier() {
    asm volatile("s_waitcnt lgkmcnt(0)" ::: "memory");
    __builtin_amdgcn_s_barrier();
}

// ---- LDS A-tile helpers (k_out only): [64][256 bf16], XOR-swizzled --------
__device__ __forceinline__ int swz(int row, int byte) { return byte ^ ((row & 7) << 4); }
__device__ __forceinline__ void st_a(__bf16* lds, int row, int cs, bf16x8 v) {
    *(bf16x8*)((char*)lds + swz(row, row * 512 + cs * 16)) = v;
}
__device__ __forceinline__ bf16x8 ld_a(const __bf16* lds, int row, int ka) {
    return *(const bf16x8*)((const char*)lds + swz(row, row * 512 + ka * 2));
}

template<int NT>
__device__ __forceinline__ void stage_f32(const float* __restrict__ A, long row0,
                                          __bf16* lds, int tid, long maxrow) {
    const int r0 = tid >> 5, cs = tid & 31;
    constexpr int RPI = NT / 32;
    #pragma unroll
    for (int i = 0; i < 64 / RPI; ++i) {
        int row = r0 + i * RPI;
        long gr = row0 + row; if (gr > maxrow) gr = maxrow;
        const float* p = A + gr * 256 + cs * 8;
        f32x4 x = *(const f32x4*)p, y = *(const f32x4*)(p + 4);
        st_a(lds, row, cs, cvt8(x, y));
    }
}

__device__ __forceinline__ void mfma_tile(const __bf16* lds, const bf16x8* __restrict__ packB,
                                          int N, int c0, int ksb,
                                          f32x4 (&acc)[4][4], int lane) {
    const int g = lane >> 4, r15 = lane & 15;
    #pragma unroll
    for (int ks = 0; ks < 8; ++ks) {
        bf16x8 a[4];
        #pragma unroll
        for (int rt = 0; rt < 4; ++rt)
            a[rt] = ld_a(lds, rt * 16 + r15, ks * 32 + g * 8);
        const size_t kb = (size_t)((ksb + ks) * 4 + g) * N;
        #pragma unroll
        for (int ct = 0; ct < 4; ++ct) {
            bf16x8 b = packB[kb + c0 + ct * 16 + r15];
            #pragma unroll
            for (int rt = 0; rt < 4; ++rt)
                acc[rt][ct] = __builtin_amdgcn_mfma_f32_16x16x32_bf16(a[rt], b, acc[rt][ct], 0, 0, 0);
        }
    }
}

// ---------------------------------------------------------------------------
__global__ __launch_bounds__(256) void k_pack(const float* __restrict__ W,
                                              __bf16* __restrict__ dst, int K, int N) {
    int idx = blockIdx.x * 256 + threadIdx.x;
    if (idx >= K * N) return;
    int k = idx / N, n = idx % N;
    dst[((size_t)(k >> 3) * N + n) * 8 + (k & 7)] = (__bf16)W[(size_t)k * N + n];
}

__global__ __launch_bounds__(256) void k_cvt(const float* __restrict__ src,
                                             __bf16* __restrict__ dst, int n4) {
    int i = blockIdx.x * 256 + threadIdx.x;
    if (i >= n4) return;
    f32x4 v = ((const f32x4*)src)[i];
    bf16x4 o;
    o[0] = (__bf16)v[0]; o[1] = (__bf16)v[1]; o[2] = (__bf16)v[2]; o[3] = (__bf16)v[3];
    ((bf16x4*)dst)[i] = o;
}

// ---------------------------------------------------------------------------
// Coarse: LE = last_equ @ W_last_equ -> LEp (MFMA D-layout, bf16).
// Barrier-free per-wave form: each wave owns 2 coarse points (32 disjoint
// rows) x 128 cols; A-frags straight from global, B from L2-resident packW.
// ---------------------------------------------------------------------------
__global__ __launch_bounds__(256) void k_coarse_equ(
    const float* __restrict__ last_equ, const bf16x8* __restrict__ packW,
    __bf16* __restrict__ LEp)
{
    const int tid = threadIdx.x, lane = tid & 63, wid = tid >> 6;
    const int h = wid & 1, m = wid >> 1;           // col-half, point-pair
    const int c0 = blockIdx.x * 4 + m * 2;         // first coarse point
    const int g = lane >> 4, r15 = lane & 15;

    f32x4 acc[2][8] = {};
    #pragma unroll
    for (int ks = 0; ks < 8; ++ks) {
        bf16x8 b[8];
        #pragma unroll
        for (int ct = 0; ct < 8; ++ct)
            b[ct] = packW[(size_t)(ks * 4 + g) * 256 + h * 128 + ct * 16 + r15];
        #pragma unroll
        for (int pt = 0; pt < 2; ++pt) {
            const float* pa = last_equ +
                ((size_t)(c0 + pt) * 16 + r15) * 256 + ks * 32 + g * 8;
            bf16x8 a = cvt8(*(const f32x4*)pa, *(const f32x4*)(pa + 4));
            #pragma unroll
            for (int ct = 0; ct < 8; ++ct)
                acc[pt][ct] = __builtin_amdgcn_mfma_f32_16x16x32_bf16(a, b[ct], acc[pt][ct], 0, 0, 0);
        }
    }
    #pragma unroll
    for (int pt = 0; pt < 2; ++pt)
        #pragma unroll
        for (int ct = 0; ct < 8; ++ct) {
            bf16x4 v;
            v[0] = (__bf16)acc[pt][ct][0]; v[1] = (__bf16)acc[pt][ct][1];
            v[2] = (__bf16)acc[pt][ct][2]; v[3] = (__bf16)acc[pt][ct][3];
            *(bf16x4*)(LEp + ((size_t)((c0 + pt) * 16 + h * 8 + ct) * 64 + lane) * 4) = v;
        }
}

// ---------------------------------------------------------------------------
// Fine fused, barrier-free: wave owns 2 fine points x 128 cols. CE GEMM with
// A-frags direct from global; LE gathers issued up-front (drain under GEMM);
// product + in-lane/shfl basis-mean -> equ (bf16). No LDS, no barriers:
// every wave self-overlaps loads and MFMA, no convoy.
// ---------------------------------------------------------------------------
__global__ __launch_bounds__(256) void k_fine_equ(
    const float* __restrict__ cur_equ, const bf16x8* __restrict__ packW,
    const __bf16* __restrict__ LEp, const int* __restrict__ up,
    __bf16* __restrict__ equ)
{
    const int tid = threadIdx.x, lane = tid & 63, wid = tid >> 6;
    const int h = wid & 1, m = wid >> 1;
    const int p0 = blockIdx.x * 4 + m * 2;
    const int g = lane >> 4, r15 = lane & 15;

    const int cu0 = up[p0], cu1 = up[p0 + 1];      // wave-uniform -> s_load

    // LE fragment gathers first: in flight across the whole GEMM
    bf16x4 le[2][8];
    #pragma unroll
    for (int ct = 0; ct < 8; ++ct)
        le[0][ct] = *(const bf16x4*)(LEp +
            ((size_t)(cu0 * 16 + h * 8 + ct) * 64 + lane) * 4);
    #pragma unroll
    for (int ct = 0; ct < 8; ++ct)
        le[1][ct] = *(const bf16x4*)(LEp +
            ((size_t)(cu1 * 16 + h * 8 + ct) * 64 + lane) * 4);

    f32x4 acc[2][8] = {};
    #pragma unroll
    for (int ks = 0; ks < 8; ++ks) {
        bf16x8 b[8];
        #pragma unroll
        for (int ct = 0; ct < 8; ++ct)
            b[ct] = packW[(size_t)(ks * 4 + g) * 256 + h * 128 + ct * 16 + r15];
        #pragma unroll
        for (int pt = 0; pt < 2; ++pt) {
            const float* pa = cur_equ +
                ((size_t)(p0 + pt) * 16 + r15) * 256 + ks * 32 + g * 8;
            bf16x8 a = cvt8(*(const f32x4*)pa, *(const f32x4*)(pa + 4));
            #pragma unroll
            for (int ct = 0; ct < 8; ++ct)
                acc[pt][ct] = __builtin_amdgcn_mfma_f32_16x16x32_bf16(a, b[ct], acc[pt][ct], 0, 0, 0);
        }
    }

    #pragma unroll
    for (int pt = 0; pt < 2; ++pt)
        #pragma unroll
        for (int ct = 0; ct < 8; ++ct) {
            float s = acc[pt][ct][0] * (float)le[pt][ct][0]
                    + acc[pt][ct][1] * (float)le[pt][ct][1]
                    + acc[pt][ct][2] * (float)le[pt][ct][2]
                    + acc[pt][ct][3] * (float)le[pt][ct][3];
            s += __shfl_xor(s, 16, 64);   // basis reduce over lane bit 4
            s += __shfl_xor(s, 32, 64);   // basis reduce over lane bit 5
            if (lane < 16)
                equ[(size_t)(p0 + pt) * 256 + h * 128 + ct * 16 + lane] =
                    (__bf16)(s * 0.0625f);
        }
}

// ---------------------------------------------------------------------------
// Output: out = [ last_inv[up] | cur_inv | equ ] @ W_mlp  (K=768)
// (round-5 structure: 512 thr, one 32-KB buffer, lgkm-only barriers)
// ---------------------------------------------------------------------------
__global__ __launch_bounds__(512) void k_out(
    const __bf16* __restrict__ li_bf, const float* __restrict__ cur_inv,
    const __bf16* __restrict__ equ, const bf16x8* __restrict__ packW,
    const int* __restrict__ up, float* __restrict__ out)
{
    __shared__ __attribute__((aligned(16))) __bf16 As[64 * 256];
    const int tid = threadIdx.x, lane = tid & 63, wid = tid >> 6;
    const int row0 = blockIdx.x * 64;
    const int c0 = wid * 64;
    const int r0 = tid >> 5, cs = tid & 31;
    f32x4 acc[4][4] = {};

    // seg0: gathered last_inv rows (bf16)
    #pragma unroll
    for (int i = 0; i < 4; ++i) {
        int row = r0 + i * 16;
        int gr = row0 + row; if (gr > N_FINE - 1) gr = N_FINE - 1;
        st_a(As, row, cs, *(const bf16x8*)(li_bf + (size_t)up[gr] * 256 + cs * 8));
    }
    lds_barrier();
    mfma_tile(As, packW, 512, c0, 0, acc, lane);
    lds_barrier();

    // seg1: cur_inv (f32)
    stage_f32<512>(cur_inv, row0, As, tid, N_FINE - 1);
    lds_barrier();
    mfma_tile(As, packW, 512, c0, 8, acc, lane);
    lds_barrier();

    // seg2: equ (bf16)
    #pragma unroll
    for (int i = 0; i < 4; ++i) {
        int row = r0 + i * 16;
        int gr = row0 + row; if (gr > N_FINE - 1) gr = N_FINE - 1;
        st_a(As, row, cs, *(const bf16x8*)(equ + (size_t)gr * 256 + cs * 8));
    }
    lds_barrier();
    mfma_tile(As, packW, 512, c0, 16, acc, lane);

    const int g = lane >> 4, r15 = lane & 15;
    #pragma unroll
    for (int rt = 0; rt < 4; ++rt)
        #pragma unroll
        for (int j = 0; j < 4; ++j) {
            int r = row0 + rt * 16 + g * 4 + j;
            if (r < N_FINE)
                #pragma unroll
                for (int ct = 0; ct < 4; ++ct)
                    out[(size_t)r * 512 + c0 + ct * 16 + r15] = acc[rt][ct][j];
        }
}

extern "C" void kernel_launch(void* const* d_in, const int* in_sizes, int n_in,
                              void* d_out, int out_size, void* d_ws, size_t ws_size,
                              hipStream_t stream) {
    const float* last_inv = (const float*)d_in[0];
    const float* cur_inv  = (const float*)d_in[1];
    const float* last_equ = (const float*)d_in[2];
    const float* cur_equ  = (const float*)d_in[3];
    const int*   up       = (const int*)d_in[4];
    const float* W_le     = (const float*)d_in[5];
    const float* W_ce     = (const float*)d_in[6];
    const float* W_mlp    = (const float*)d_in[7];
    float* out = (float*)d_out;

    // workspace carve-up (~135 MB)
    char* w = (char*)d_ws;
    __bf16* LEp    = (__bf16*)w;  w += (size_t)N_COARSE * 16 * 256 * 2;  // 102.4 MB
    __bf16* equ    = (__bf16*)w;  w += (size_t)N_FINE * 256 * 2;        //  25.6 MB
    __bf16* li_bf  = (__bf16*)w;  w += (size_t)N_COARSE * 256 * 2;      //   6.4 MB
    __bf16* packLE = (__bf16*)w;  w += (size_t)256 * 256 * 2;
    __bf16* packCE = (__bf16*)w;  w += (size_t)256 * 256 * 2;
    __bf16* packM  = (__bf16*)w;  w += (size_t)768 * 512 * 2;

    k_pack<<<256, 256, 0, stream>>>(W_le, packLE, 256, 256);
    k_pack<<<256, 256, 0, stream>>>(W_ce, packCE, 256, 256);
    k_pack<<<1536, 256, 0, stream>>>(W_mlp, packM, 768, 512);
    k_cvt<<<3125, 256, 0, stream>>>(last_inv, li_bf, N_COARSE * 256 / 4);

    k_coarse_equ<<<N_COARSE / 4, 256, 0, stream>>>(
        last_equ, (const bf16x8*)packLE, LEp);

    k_fine_equ<<<N_FINE / 4, 256, 0, stream>>>(
        cur_equ, (const bf16x8*)packCE, LEp, up, equ);

    k_out<<<(N_FINE + 63) / 64, 512, 0, stream>>>(
        li_bf, cur_inv, equ, (const bf16x8*)packM, up, out);
}

// Round 9
// 630.896 us; speedup vs baseline: 1.0280x; 1.0280x over previous
//
#include <hip/hip_runtime.h>
#include <hip/hip_bf16.h>

#define N_COARSE 12500
#define N_FINE   50000

typedef __bf16 bf16x8 __attribute__((ext_vector_type(8)));
typedef __bf16 bf16x4 __attribute__((ext_vector_type(4)));
typedef float  f32x4  __attribute__((ext_vector_type(4)));

// ---------------------------------------------------------------------------
// Fragment conventions (v_mfma_f32_16x16x32_bf16), HW-verified:
//   a-frag: lane holds A[row = lane&15][k = (lane>>4)*8 + j]
//   b-frag: lane holds B[k = (lane>>4)*8 + j][col = lane&15]
//   d     : lane holds D[row = (lane>>4)*4 + j][col = lane&15]
// ---------------------------------------------------------------------------

__device__ __forceinline__ bf16x8 cvt8(f32x4 x, f32x4 y) {
    bf16x8 r;
    r[0] = (__bf16)x[0]; r[1] = (__bf16)x[1]; r[2] = (__bf16)x[2]; r[3] = (__bf16)x[3];
    r[4] = (__bf16)y[0]; r[5] = (__bf16)y[1]; r[6] = (__bf16)y[2]; r[7] = (__bf16)y[3];
    return r;
}

// Barrier with LDS-only fence (avoids __syncthreads' vmcnt(0) drain so
// prefetch loads stay in flight across the barrier).
__device__ __forceinline__ void lds_barrier() {
    asm volatile("s_waitcnt lgkmcnt(0)" ::: "memory");
    __builtin_amdgcn_s_barrier();
}

// ---- LDS A-tile, XOR-swizzled (row stride 512 B) --------------------------
__device__ __forceinline__ int swz(int row, int byte) { return byte ^ ((row & 7) << 4); }
__device__ __forceinline__ void st_a(__bf16* lds, int row, int cs, bf16x8 v) {
    *(bf16x8*)((char*)lds + swz(row, row * 512 + cs * 16)) = v;
}
__device__ __forceinline__ bf16x8 ld_a(const __bf16* lds, int row, int ka) {
    return *(const bf16x8*)((const char*)lds + swz(row, row * 512 + ka * 2));
}

template<int NT>
__device__ __forceinline__ void stage_f32(const float* __restrict__ A, long row0,
                                          __bf16* lds, int tid, long maxrow) {
    const int r0 = tid >> 5, cs = tid & 31;
    constexpr int RPI = NT / 32;
    #pragma unroll
    for (int i = 0; i < 64 / RPI; ++i) {
        int row = r0 + i * RPI;
        long gr = row0 + row; if (gr > maxrow) gr = maxrow;
        const float* p = A + gr * 256 + cs * 8;
        f32x4 x = *(const f32x4*)p, y = *(const f32x4*)(p + 4);
        st_a(lds, row, cs, cvt8(x, y));
    }
}

// 64x64-per-wave MFMA over one 256-wide K segment (64-row tiles; k_coarse/k_out)
__device__ __forceinline__ void mfma_tile(const __bf16* lds, const bf16x8* __restrict__ packB,
                                          int N, int c0, int ksb,
                                          f32x4 (&acc)[4][4], int lane) {
    const int g = lane >> 4, r15 = lane & 15;
    #pragma unroll
    for (int ks = 0; ks < 8; ++ks) {
        bf16x8 a[4];
        #pragma unroll
        for (int rt = 0; rt < 4; ++rt)
            a[rt] = ld_a(lds, rt * 16 + r15, ks * 32 + g * 8);
        const size_t kb = (size_t)((ksb + ks) * 4 + g) * N;
        #pragma unroll
        for (int ct = 0; ct < 4; ++ct) {
            bf16x8 b = packB[kb + c0 + ct * 16 + r15];
            #pragma unroll
            for (int rt = 0; rt < 4; ++rt)
                acc[rt][ct] = __builtin_amdgcn_mfma_f32_16x16x32_bf16(a[rt], b, acc[rt][ct], 0, 0, 0);
        }
    }
}

// ---------------------------------------------------------------------------
__global__ __launch_bounds__(256) void k_pack(const float* __restrict__ W,
                                              __bf16* __restrict__ dst, int K, int N) {
    int idx = blockIdx.x * 256 + threadIdx.x;
    if (idx >= K * N) return;
    int k = idx / N, n = idx % N;
    dst[((size_t)(k >> 3) * N + n) * 8 + (k & 7)] = (__bf16)W[(size_t)k * N + n];
}

__global__ __launch_bounds__(256) void k_cvt(const float* __restrict__ src,
                                             __bf16* __restrict__ dst, int n4) {
    int i = blockIdx.x * 256 + threadIdx.x;
    if (i >= n4) return;
    f32x4 v = ((const f32x4*)src)[i];
    bf16x4 o;
    o[0] = (__bf16)v[0]; o[1] = (__bf16)v[1]; o[2] = (__bf16)v[2]; o[3] = (__bf16)v[3];
    ((bf16x4*)dst)[i] = o;
}

// ---------------------------------------------------------------------------
// Coarse: LE = last_equ @ W_last_equ -> LEp (MFMA D-layout, bf16).
// Round-5 one-shot form (best measured).
// ---------------------------------------------------------------------------
__global__ __launch_bounds__(256) void k_coarse_equ(
    const float* __restrict__ last_equ, const bf16x8* __restrict__ packW,
    __bf16* __restrict__ LEp)
{
    __shared__ __attribute__((aligned(16))) __bf16 As[64 * 256];
    const int tid = threadIdx.x, lane = tid & 63, wid = tid >> 6;
    const long row0 = (long)blockIdx.x * 64;
    stage_f32<256>(last_equ, row0, As, tid, (long)N_COARSE * 16 - 1);
    lds_barrier();
    f32x4 acc[4][4] = {};
    mfma_tile(As, packW, 256, wid * 64, 0, acc, lane);
    #pragma unroll
    for (int rt = 0; rt < 4; ++rt) {
        int coarse = (int)(row0 >> 4) + rt;
        #pragma unroll
        for (int ct = 0; ct < 4; ++ct) {
            int cg = wid * 4 + ct;
            bf16x4 v;
            v[0] = (__bf16)acc[rt][ct][0]; v[1] = (__bf16)acc[rt][ct][1];
            v[2] = (__bf16)acc[rt][ct][2]; v[3] = (__bf16)acc[rt][ct][3];
            *(bf16x4*)(LEp + ((size_t)(coarse * 16 + cg) * 64 + lane) * 4) = v;
        }
    }
}

// ---------------------------------------------------------------------------
// Fine fused: 32-row tiles (2 points), double-buffered 2x16KB LDS, 4 tiles
// per block. Per iteration: lgkm-barrier -> issue next-tile loads + LE
// gathers (stay in flight, counted vmcnt) -> MFMA(cur) -> epilogue ->
// ds_write(next). Occupancy-neutral vs round-5 (acc/le halved pays for
// the 32 prefetch regs); launch_bounds(256,4) pins 4 waves/SIMD.
// ---------------------------------------------------------------------------
__global__ __launch_bounds__(256, 4) void k_fine_equ(
    const float* __restrict__ cur_equ, const bf16x8* __restrict__ packW,
    const __bf16* __restrict__ LEp, const int* __restrict__ up,
    __bf16* __restrict__ equ)
{
    __shared__ __attribute__((aligned(16))) __bf16 As[2][32 * 256];
    const int tid = threadIdx.x, lane = tid & 63, wid = tid >> 6;
    const int pbase = blockIdx.x * 8;            // 8 fine points = 4 tiles
    const int r0 = tid >> 5, cs = tid & 31;
    const int g = lane >> 4, r15 = lane & 15;

    f32x4 x[4], y[4];
    // prologue: stage tile 0
    #pragma unroll
    for (int i = 0; i < 4; ++i) {
        const float* p = cur_equ + ((long)pbase * 16 + i * 8 + r0) * 256 + cs * 8;
        x[i] = *(const f32x4*)p; y[i] = *(const f32x4*)(p + 4);
    }
    #pragma unroll
    for (int i = 0; i < 4; ++i) st_a(As[0], i * 8 + r0, cs, cvt8(x[i], y[i]));

    #pragma unroll
    for (int t = 0; t < 4; ++t) {
        const int cur = t & 1;
        lds_barrier();                            // tile t ready (lgkm only)
        if (t < 3) {                              // issue next-tile loads
            #pragma unroll
            for (int i = 0; i < 4; ++i) {
                const float* p = cur_equ +
                    ((long)(pbase + (t + 1) * 2) * 16 + i * 8 + r0) * 256 + cs * 8;
                x[i] = *(const f32x4*)p; y[i] = *(const f32x4*)(p + 4);
            }
        }
        const int p0 = pbase + t * 2;
        const int cu0 = up[p0], cu1 = up[p0 + 1]; // uniform -> s_load
        bf16x4 le[2][4];
        #pragma unroll
        for (int ct = 0; ct < 4; ++ct) {
            le[0][ct] = *(const bf16x4*)(LEp +
                ((size_t)(cu0 * 16 + wid * 4 + ct) * 64 + lane) * 4);
            le[1][ct] = *(const bf16x4*)(LEp +
                ((size_t)(cu1 * 16 + wid * 4 + ct) * 64 + lane) * 4);
        }

        f32x4 acc[2][4] = {};
        #pragma unroll
        for (int ks = 0; ks < 8; ++ks) {
            bf16x8 a0 = ld_a(As[cur], r15,      ks * 32 + g * 8);
            bf16x8 a1 = ld_a(As[cur], 16 + r15, ks * 32 + g * 8);
            #pragma unroll
            for (int ct = 0; ct < 4; ++ct) {
                bf16x8 b = packW[(size_t)(ks * 4 + g) * 256 + wid * 64 + ct * 16 + r15];
                acc[0][ct] = __builtin_amdgcn_mfma_f32_16x16x32_bf16(a0, b, acc[0][ct], 0, 0, 0);
                acc[1][ct] = __builtin_amdgcn_mfma_f32_16x16x32_bf16(a1, b, acc[1][ct], 0, 0, 0);
            }
        }

        #pragma unroll
        for (int pt = 0; pt < 2; ++pt)
            #pragma unroll
            for (int ct = 0; ct < 4; ++ct) {
                float s = acc[pt][ct][0] * (float)le[pt][ct][0]
                        + acc[pt][ct][1] * (float)le[pt][ct][1]
                        + acc[pt][ct][2] * (float)le[pt][ct][2]
                        + acc[pt][ct][3] * (float)le[pt][ct][3];
                s += __shfl_xor(s, 16, 64);   // basis reduce over lane bit 4
                s += __shfl_xor(s, 32, 64);   // basis reduce over lane bit 5
                if (lane < 16)
                    equ[(size_t)(p0 + pt) * 256 + wid * 64 + ct * 16 + lane] =
                        (__bf16)(s * 0.0625f);
            }

        if (t < 3) {                              // write next tile (waits its loads)
            #pragma unroll
            for (int i = 0; i < 4; ++i)
                st_a(As[cur ^ 1], i * 8 + r0, cs, cvt8(x[i], y[i]));
        }
    }
}

// ---------------------------------------------------------------------------
// Output: out = [ last_inv[up] | cur_inv | equ ] @ W_mlp  (K=768)
// Round-5 form: 512 thr, one 32-KB buffer, lgkm-only barriers.
// ---------------------------------------------------------------------------
__global__ __launch_bounds__(512) void k_out(
    const __bf16* __restrict__ li_bf, const float* __restrict__ cur_inv,
    const __bf16* __restrict__ equ, const bf16x8* __restrict__ packW,
    const int* __restrict__ up, float* __restrict__ out)
{
    __shared__ __attribute__((aligned(16))) __bf16 As[64 * 256];
    const int tid = threadIdx.x, lane = tid & 63, wid = tid >> 6;
    const int row0 = blockIdx.x * 64;
    const int c0 = wid * 64;
    const int r0 = tid >> 5, cs = tid & 31;
    f32x4 acc[4][4] = {};

    // seg0: gathered last_inv rows (bf16)
    #pragma unroll
    for (int i = 0; i < 4; ++i) {
        int row = r0 + i * 16;
        int gr = row0 + row; if (gr > N_FINE - 1) gr = N_FINE - 1;
        st_a(As, row, cs, *(const bf16x8*)(li_bf + (size_t)up[gr] * 256 + cs * 8));
    }
    lds_barrier();
    mfma_tile(As, packW, 512, c0, 0, acc, lane);
    lds_barrier();

    // seg1: cur_inv (f32)
    stage_f32<512>(cur_inv, row0, As, tid, N_FINE - 1);
    lds_barrier();
    mfma_tile(As, packW, 512, c0, 8, acc, lane);
    lds_barrier();

    // seg2: equ (bf16)
    #pragma unroll
    for (int i = 0; i < 4; ++i) {
        int row = r0 + i * 16;
        int gr = row0 + row; if (gr > N_FINE - 1) gr = N_FINE - 1;
        st_a(As, row, cs, *(const bf16x8*)(equ + (size_t)gr * 256 + cs * 8));
    }
    lds_barrier();
    mfma_tile(As, packW, 512, c0, 16, acc, lane);

    const int g = lane >> 4, r15 = lane & 15;
    #pragma unroll
    for (int rt = 0; rt < 4; ++rt)
        #pragma unroll
        for (int j = 0; j < 4; ++j) {
            int r = row0 + rt * 16 + g * 4 + j;
            if (r < N_FINE)
                #pragma unroll
                for (int ct = 0; ct < 4; ++ct)
                    out[(size_t)r * 512 + c0 + ct * 16 + r15] = acc[rt][ct][j];
        }
}

extern "C" void kernel_launch(void* const* d_in, const int* in_sizes, int n_in,
                              void* d_out, int out_size, void* d_ws, size_t ws_size,
                              hipStream_t stream) {
    const float* last_inv = (const float*)d_in[0];
    const float* cur_inv  = (const float*)d_in[1];
    const float* last_equ = (const float*)d_in[2];
    const float* cur_equ  = (const float*)d_in[3];
    const int*   up       = (const int*)d_in[4];
    const float* W_le     = (const float*)d_in[5];
    const float* W_ce     = (const float*)d_in[6];
    const float* W_mlp    = (const float*)d_in[7];
    float* out = (float*)d_out;

    // workspace carve-up (~135 MB)
    char* w = (char*)d_ws;
    __bf16* LEp    = (__bf16*)w;  w += (size_t)N_COARSE * 16 * 256 * 2;  // 102.4 MB
    __bf16* equ    = (__bf16*)w;  w += (size_t)N_FINE * 256 * 2;        //  25.6 MB
    __bf16* li_bf  = (__bf16*)w;  w += (size_t)N_COARSE * 256 * 2;      //   6.4 MB
    __bf16* packLE = (__bf16*)w;  w += (size_t)256 * 256 * 2;
    __bf16* packCE = (__bf16*)w;  w += (size_t)256 * 256 * 2;
    __bf16* packM  = (__bf16*)w;  w += (size_t)768 * 512 * 2;

    k_pack<<<256, 256, 0, stream>>>(W_le, packLE, 256, 256);
    k_pack<<<256, 256, 0, stream>>>(W_ce, packCE, 256, 256);
    k_pack<<<1536, 256, 0, stream>>>(W_mlp, packM, 768, 512);
    k_cvt<<<3125, 256, 0, stream>>>(last_inv, li_bf, N_COARSE * 256 / 4);

    k_coarse_equ<<<N_COARSE * 16 / 64, 256, 0, stream>>>(
        last_equ, (const bf16x8*)packLE, LEp);

    k_fine_equ<<<N_FINE / 8, 256, 0, stream>>>(
        cur_equ, (const bf16x8*)packCE, LEp, up, equ);

    k_out<<<(N_FINE + 63) / 64, 512, 0, stream>>>(
        li_bf, cur_inv, equ, (const bf16x8*)packM, up, out);
}

// Round 10
// 553.836 us; speedup vs baseline: 1.1710x; 1.1391x over previous
//
#include <hip/hip_runtime.h>
#include <hip/hip_bf16.h>

#define N_COARSE 12500
#define N_FINE   50000

typedef __bf16 bf16x8 __attribute__((ext_vector_type(8)));
typedef __bf16 bf16x4 __attribute__((ext_vector_type(4)));
typedef float  f32x4  __attribute__((ext_vector_type(4)));

// ---------------------------------------------------------------------------
// Fragment conventions (v_mfma_f32_16x16x32_bf16), HW-verified:
//   a-frag: lane holds A[row = lane&15][k = (lane>>4)*8 + j]
//   b-frag: lane holds B[k = (lane>>4)*8 + j][col = lane&15]
//   d     : lane holds D[row = (lane>>4)*4 + j][col = lane&15]
// ---------------------------------------------------------------------------

__device__ __forceinline__ bf16x8 cvt8(f32x4 x, f32x4 y) {
    bf16x8 r;
    r[0] = (__bf16)x[0]; r[1] = (__bf16)x[1]; r[2] = (__bf16)x[2]; r[3] = (__bf16)x[3];
    r[4] = (__bf16)y[0]; r[5] = (__bf16)y[1]; r[6] = (__bf16)y[2]; r[7] = (__bf16)y[3];
    return r;
}

// Barrier with LDS-only fence (avoids __syncthreads' vmcnt(0) drain).
__device__ __forceinline__ void lds_barrier() {
    asm volatile("s_waitcnt lgkmcnt(0)" ::: "memory");
    __builtin_amdgcn_s_barrier();
}

// ---- LDS A-tile: [64 rows][256 bf16] = 32 KB, XOR-swizzled ----------------
__device__ __forceinline__ int swz(int row, int byte) { return byte ^ ((row & 7) << 4); }
__device__ __forceinline__ void st_a(__bf16* lds, int row, int cs, bf16x8 v) {
    *(bf16x8*)((char*)lds + swz(row, row * 512 + cs * 16)) = v;
}
__device__ __forceinline__ bf16x8 ld_a(const __bf16* lds, int row, int ka) {
    return *(const bf16x8*)((const char*)lds + swz(row, row * 512 + ka * 2));
}

template<int NT>
__device__ __forceinline__ void stage_f32(const float* __restrict__ A, long row0,
                                          __bf16* lds, int tid, long maxrow) {
    const int r0 = tid >> 5, cs = tid & 31;
    constexpr int RPI = NT / 32;
    #pragma unroll
    for (int i = 0; i < 64 / RPI; ++i) {
        int row = r0 + i * RPI;
        long gr = row0 + row; if (gr > maxrow) gr = maxrow;
        const float* p = A + gr * 256 + cs * 8;
        f32x4 x = *(const f32x4*)p, y = *(const f32x4*)(p + 4);
        st_a(lds, row, cs, cvt8(x, y));
    }
}

// 64x64-per-wave MFMA over one 256-wide K segment, A from LDS, B packed global
__device__ __forceinline__ void mfma_tile(const __bf16* lds, const bf16x8* __restrict__ packB,
                                          int N, int c0, int ksb,
                                          f32x4 (&acc)[4][4], int lane) {
    const int g = lane >> 4, r15 = lane & 15;
    #pragma unroll
    for (int ks = 0; ks < 8; ++ks) {
        bf16x8 a[4];
        #pragma unroll
        for (int rt = 0; rt < 4; ++rt)
            a[rt] = ld_a(lds, rt * 16 + r15, ks * 32 + g * 8);
        const size_t kb = (size_t)((ksb + ks) * 4 + g) * N;
        #pragma unroll
        for (int ct = 0; ct < 4; ++ct) {
            bf16x8 b = packB[kb + c0 + ct * 16 + r15];
            #pragma unroll
            for (int rt = 0; rt < 4; ++rt)
                acc[rt][ct] = __builtin_amdgcn_mfma_f32_16x16x32_bf16(a[rt], b, acc[rt][ct], 0, 0, 0);
        }
    }
}

// ---------------------------------------------------------------------------
// Merged prep: pack W_le / W_ce / W_mlp into MFMA b-frag layout + cvt last_inv
// to bf16. One launch instead of four.
// Pack layout: dst[((k>>3)*N + n)*8 + (k&7)] = (bf16)W[k*N + n]
// ---------------------------------------------------------------------------
__global__ __launch_bounds__(256) void k_prep(
    const float* __restrict__ W_le, const float* __restrict__ W_ce,
    const float* __restrict__ W_mlp, const float* __restrict__ last_inv,
    __bf16* __restrict__ packLE, __bf16* __restrict__ packCE,
    __bf16* __restrict__ packM, __bf16* __restrict__ li_bf)
{
    const int b = blockIdx.x, tid = threadIdx.x;
    if (b < 256) {                       // W_le pack (256x256)
        int idx = b * 256 + tid, k = idx >> 8, n = idx & 255;
        packLE[(((size_t)(k >> 3) << 8) + n) * 8 + (k & 7)] = (__bf16)W_le[idx];
    } else if (b < 512) {                // W_ce pack (256x256)
        int idx = (b - 256) * 256 + tid, k = idx >> 8, n = idx & 255;
        packCE[(((size_t)(k >> 3) << 8) + n) * 8 + (k & 7)] = (__bf16)W_ce[idx];
    } else if (b < 2048) {               // W_mlp pack (768x512)
        int idx = (b - 512) * 256 + tid, k = idx >> 9, n = idx & 511;
        packM[(((size_t)(k >> 3) << 9) + n) * 8 + (k & 7)] = (__bf16)W_mlp[idx];
    } else {                             // last_inv f32 -> bf16 (800000 x4 chunks)
        int i = (b - 2048) * 256 + tid;
        f32x4 v = ((const f32x4*)last_inv)[i];
        bf16x4 o;
        o[0] = (__bf16)v[0]; o[1] = (__bf16)v[1]; o[2] = (__bf16)v[2]; o[3] = (__bf16)v[3];
        ((bf16x4*)li_bf)[i] = o;
    }
}

// ---------------------------------------------------------------------------
// Coarse: LE = last_equ @ W_last_equ -> LEp (MFMA D-layout, bf16). R5 form.
// ---------------------------------------------------------------------------
__global__ __launch_bounds__(256) void k_coarse_equ(
    const float* __restrict__ last_equ, const bf16x8* __restrict__ packW,
    __bf16* __restrict__ LEp)
{
    __shared__ __attribute__((aligned(16))) __bf16 As[64 * 256];
    const int tid = threadIdx.x, lane = tid & 63, wid = tid >> 6;
    const long row0 = (long)blockIdx.x * 64;
    stage_f32<256>(last_equ, row0, As, tid, (long)N_COARSE * 16 - 1);
    lds_barrier();
    f32x4 acc[4][4] = {};
    mfma_tile(As, packW, 256, wid * 64, 0, acc, lane);
    #pragma unroll
    for (int rt = 0; rt < 4; ++rt) {
        int coarse = (int)(row0 >> 4) + rt;
        #pragma unroll
        for (int ct = 0; ct < 4; ++ct) {
            int cg = wid * 4 + ct;
            bf16x4 v;
            v[0] = (__bf16)acc[rt][ct][0]; v[1] = (__bf16)acc[rt][ct][1];
            v[2] = (__bf16)acc[rt][ct][2]; v[3] = (__bf16)acc[rt][ct][3];
            *(bf16x4*)(LEp + ((size_t)(coarse * 16 + cg) * 64 + lane) * 4) = v;
        }
    }
}

// ---------------------------------------------------------------------------
// Fine fused (R5 one-shot, VGPR-dieted): LE gathers moved AFTER the MFMA
// loop so their 32 destination VGPRs are not live across it. Peak live set
// ~105 VGPR -> 4-5 waves/SIMD (was 3): more cross-block TLP, which is the
// only latency-hiding mechanism that has paid off on this op (R4/R8/R9
// intra-block variants all regressed).
// ---------------------------------------------------------------------------
__global__ __launch_bounds__(256) void k_fine_equ(
    const float* __restrict__ cur_equ, const bf16x8* __restrict__ packW,
    const __bf16* __restrict__ LEp, const int* __restrict__ up,
    __bf16* __restrict__ equ)
{
    __shared__ __attribute__((aligned(16))) __bf16 As[64 * 256];
    const int tid = threadIdx.x, lane = tid & 63, wid = tid >> 6;
    const int n0 = blockIdx.x * 4;
    const long row0 = (long)blockIdx.x * 64;

    int cu[4];
    #pragma unroll
    for (int rt = 0; rt < 4; ++rt) cu[rt] = up[n0 + rt];   // uniform -> s_load

    stage_f32<256>(cur_equ, row0, As, tid, (long)N_FINE * 16 - 1);
    lds_barrier();

    f32x4 acc[4][4] = {};
    mfma_tile(As, packW, 256, wid * 64, 0, acc, lane);

    // LE fragment gathers (post-MFMA: L3-resident table, short tail)
    bf16x4 le[4][4];
    #pragma unroll
    for (int rt = 0; rt < 4; ++rt)
        #pragma unroll
        for (int ct = 0; ct < 4; ++ct)
            le[rt][ct] = *(const bf16x4*)(LEp +
                ((size_t)(cu[rt] * 16 + wid * 4 + ct) * 64 + lane) * 4);

    #pragma unroll
    for (int rt = 0; rt < 4; ++rt) {
        int n = n0 + rt;
        #pragma unroll
        for (int ct = 0; ct < 4; ++ct) {
            float s = acc[rt][ct][0] * (float)le[rt][ct][0]
                    + acc[rt][ct][1] * (float)le[rt][ct][1]
                    + acc[rt][ct][2] * (float)le[rt][ct][2]
                    + acc[rt][ct][3] * (float)le[rt][ct][3];
            s += __shfl_xor(s, 16, 64);   // basis reduce over lane bit 4
            s += __shfl_xor(s, 32, 64);   // basis reduce over lane bit 5
            if (lane < 16)
                equ[(size_t)n * 256 + wid * 64 + ct * 16 + lane] = (__bf16)(s * 0.0625f);
        }
    }
}

// ---------------------------------------------------------------------------
// Output: out = [ last_inv[up] | cur_inv | equ ] @ W_mlp  (K=768). R5 form.
// ---------------------------------------------------------------------------
__global__ __launch_bounds__(512) void k_out(
    const __bf16* __restrict__ li_bf, const float* __restrict__ cur_inv,
    const __bf16* __restrict__ equ, const bf16x8* __restrict__ packW,
    const int* __restrict__ up, float* __restrict__ out)
{
    __shared__ __attribute__((aligned(16))) __bf16 As[64 * 256];
    const int tid = threadIdx.x, lane = tid & 63, wid = tid >> 6;
    const int row0 = blockIdx.x * 64;
    const int c0 = wid * 64;
    const int r0 = tid >> 5, cs = tid & 31;
    f32x4 acc[4][4] = {};

    // seg0: gathered last_inv rows (bf16)
    #pragma unroll
    for (int i = 0; i < 4; ++i) {
        int row = r0 + i * 16;
        int gr = row0 + row; if (gr > N_FINE - 1) gr = N_FINE - 1;
        st_a(As, row, cs, *(const bf16x8*)(li_bf + (size_t)up[gr] * 256 + cs * 8));
    }
    lds_barrier();
    mfma_tile(As, packW, 512, c0, 0, acc, lane);
    lds_barrier();

    // seg1: cur_inv (f32)
    stage_f32<512>(cur_inv, row0, As, tid, N_FINE - 1);
    lds_barrier();
    mfma_tile(As, packW, 512, c0, 8, acc, lane);
    lds_barrier();

    // seg2: equ (bf16)
    #pragma unroll
    for (int i = 0; i < 4; ++i) {
        int row = r0 + i * 16;
        int gr = row0 + row; if (gr > N_FINE - 1) gr = N_FINE - 1;
        st_a(As, row, cs, *(const bf16x8*)(equ + (size_t)gr * 256 + cs * 8));
    }
    lds_barrier();
    mfma_tile(As, packW, 512, c0, 16, acc, lane);

    const int g = lane >> 4, r15 = lane & 15;
    #pragma unroll
    for (int rt = 0; rt < 4; ++rt)
        #pragma unroll
        for (int j = 0; j < 4; ++j) {
            int r = row0 + rt * 16 + g * 4 + j;
            if (r < N_FINE)
                #pragma unroll
                for (int ct = 0; ct < 4; ++ct)
                    out[(size_t)r * 512 + c0 + ct * 16 + r15] = acc[rt][ct][j];
        }
}

extern "C" void kernel_launch(void* const* d_in, const int* in_sizes, int n_in,
                              void* d_out, int out_size, void* d_ws, size_t ws_size,
                              hipStream_t stream) {
    const float* last_inv = (const float*)d_in[0];
    const float* cur_inv  = (const float*)d_in[1];
    const float* last_equ = (const float*)d_in[2];
    const float* cur_equ  = (const float*)d_in[3];
    const int*   up       = (const int*)d_in[4];
    const float* W_le     = (const float*)d_in[5];
    const float* W_ce     = (const float*)d_in[6];
    const float* W_mlp    = (const float*)d_in[7];
    float* out = (float*)d_out;

    // workspace carve-up (~135 MB)
    char* w = (char*)d_ws;
    __bf16* LEp    = (__bf16*)w;  w += (size_t)N_COARSE * 16 * 256 * 2;  // 102.4 MB
    __bf16* equ    = (__bf16*)w;  w += (size_t)N_FINE * 256 * 2;        //  25.6 MB
    __bf16* li_bf  = (__bf16*)w;  w += (size_t)N_COARSE * 256 * 2;      //   6.4 MB
    __bf16* packLE = (__bf16*)w;  w += (size_t)256 * 256 * 2;
    __bf16* packCE = (__bf16*)w;  w += (size_t)256 * 256 * 2;
    __bf16* packM  = (__bf16*)w;  w += (size_t)768 * 512 * 2;

    // merged prep: 256 + 256 + 1536 + 3125 blocks
    k_prep<<<2048 + 3125, 256, 0, stream>>>(
        W_le, W_ce, W_mlp, last_inv, packLE, packCE, packM, li_bf);

    k_coarse_equ<<<N_COARSE * 16 / 64, 256, 0, stream>>>(
        last_equ, (const bf16x8*)packLE, LEp);

    k_fine_equ<<<N_FINE / 4, 256, 0, stream>>>(
        cur_equ, (const bf16x8*)packCE, LEp, up, equ);

    k_out<<<(N_FINE + 63) / 64, 512, 0, stream>>>(
        li_bf, cur_inv, equ, (const bf16x8*)packM, up, out);
}

// Round 11
// 552.986 us; speedup vs baseline: 1.1728x; 1.0015x over previous
//
#include <hip/hip_runtime.h>
#include <hip/hip_bf16.h>

#define N_COARSE 12500
#define N_FINE   50000

typedef __bf16 bf16x8 __attribute__((ext_vector_type(8)));
typedef __bf16 bf16x4 __attribute__((ext_vector_type(4)));
typedef float  f32x4  __attribute__((ext_vector_type(4)));

// ---------------------------------------------------------------------------
// Fragment conventions (v_mfma_f32_16x16x32_bf16), HW-verified:
//   a-frag: lane holds A[row = lane&15][k = (lane>>4)*8 + j]
//   b-frag: lane holds B[k = (lane>>4)*8 + j][col = lane&15]
//   d     : lane holds D[row = (lane>>4)*4 + j][col = lane&15]
// ---------------------------------------------------------------------------

__device__ __forceinline__ bf16x8 cvt8(f32x4 x, f32x4 y) {
    bf16x8 r;
    r[0] = (__bf16)x[0]; r[1] = (__bf16)x[1]; r[2] = (__bf16)x[2]; r[3] = (__bf16)x[3];
    r[4] = (__bf16)y[0]; r[5] = (__bf16)y[1]; r[6] = (__bf16)y[2]; r[7] = (__bf16)y[3];
    return r;
}

// Barrier with LDS-only fence (avoids __syncthreads' vmcnt(0) drain).
__device__ __forceinline__ void lds_barrier() {
    asm volatile("s_waitcnt lgkmcnt(0)" ::: "memory");
    __builtin_amdgcn_s_barrier();
}

// ---- LDS A-tile: [64 rows][256 bf16] = 32 KB, XOR-swizzled ----------------
__device__ __forceinline__ int swz(int row, int byte) { return byte ^ ((row & 7) << 4); }
__device__ __forceinline__ void st_a(__bf16* lds, int row, int cs, bf16x8 v) {
    *(bf16x8*)((char*)lds + swz(row, row * 512 + cs * 16)) = v;
}
__device__ __forceinline__ bf16x8 ld_a(const __bf16* lds, int row, int ka) {
    return *(const bf16x8*)((const char*)lds + swz(row, row * 512 + ka * 2));
}

template<int NT>
__device__ __forceinline__ void stage_f32(const float* __restrict__ A, long row0,
                                          __bf16* lds, int tid, long maxrow) {
    const int r0 = tid >> 5, cs = tid & 31;
    constexpr int RPI = NT / 32;
    #pragma unroll
    for (int i = 0; i < 64 / RPI; ++i) {
        int row = r0 + i * RPI;
        long gr = row0 + row; if (gr > maxrow) gr = maxrow;
        const float* p = A + gr * 256 + cs * 8;
        f32x4 x = *(const f32x4*)p, y = *(const f32x4*)(p + 4);
        st_a(lds, row, cs, cvt8(x, y));
    }
}

// 64x64-per-wave MFMA over one 256-wide K segment, A from LDS, B packed global
__device__ __forceinline__ void mfma_tile(const __bf16* lds, const bf16x8* __restrict__ packB,
                                          int N, int c0, int ksb,
                                          f32x4 (&acc)[4][4], int lane) {
    const int g = lane >> 4, r15 = lane & 15;
    #pragma unroll
    for (int ks = 0; ks < 8; ++ks) {
        bf16x8 a[4];
        #pragma unroll
        for (int rt = 0; rt < 4; ++rt)
            a[rt] = ld_a(lds, rt * 16 + r15, ks * 32 + g * 8);
        const size_t kb = (size_t)((ksb + ks) * 4 + g) * N;
        #pragma unroll
        for (int ct = 0; ct < 4; ++ct) {
            bf16x8 b = packB[kb + c0 + ct * 16 + r15];
            #pragma unroll
            for (int rt = 0; rt < 4; ++rt)
                acc[rt][ct] = __builtin_amdgcn_mfma_f32_16x16x32_bf16(a[rt], b, acc[rt][ct], 0, 0, 0);
        }
    }
}

// ---------------------------------------------------------------------------
// Merged prep: pack W_le / W_ce / W_mlp into MFMA b-frag layout + cvt last_inv
// to bf16. One launch instead of four.
// Pack layout: dst[((k>>3)*N + n)*8 + (k&7)] = (bf16)W[k*N + n]
// ---------------------------------------------------------------------------
__global__ __launch_bounds__(256) void k_prep(
    const float* __restrict__ W_le, const float* __restrict__ W_ce,
    const float* __restrict__ W_mlp, const float* __restrict__ last_inv,
    __bf16* __restrict__ packLE, __bf16* __restrict__ packCE,
    __bf16* __restrict__ packM, __bf16* __restrict__ li_bf)
{
    const int b = blockIdx.x, tid = threadIdx.x;
    if (b < 256) {                       // W_le pack (256x256)
        int idx = b * 256 + tid, k = idx >> 8, n = idx & 255;
        packLE[(((size_t)(k >> 3) << 8) + n) * 8 + (k & 7)] = (__bf16)W_le[idx];
    } else if (b < 512) {                // W_ce pack (256x256)
        int idx = (b - 256) * 256 + tid, k = idx >> 8, n = idx & 255;
        packCE[(((size_t)(k >> 3) << 8) + n) * 8 + (k & 7)] = (__bf16)W_ce[idx];
    } else if (b < 2048) {               // W_mlp pack (768x512)
        int idx = (b - 512) * 256 + tid, k = idx >> 9, n = idx & 511;
        packM[(((size_t)(k >> 3) << 9) + n) * 8 + (k & 7)] = (__bf16)W_mlp[idx];
    } else {                             // last_inv f32 -> bf16 (800000 x4 chunks)
        int i = (b - 2048) * 256 + tid;
        f32x4 v = ((const f32x4*)last_inv)[i];
        bf16x4 o;
        o[0] = (__bf16)v[0]; o[1] = (__bf16)v[1]; o[2] = (__bf16)v[2]; o[3] = (__bf16)v[3];
        ((bf16x4*)li_bf)[i] = o;
    }
}

// ---------------------------------------------------------------------------
// Coarse: LE = last_equ @ W_last_equ -> LEp (MFMA D-layout, bf16). R5 form.
// ---------------------------------------------------------------------------
__global__ __launch_bounds__(256) void k_coarse_equ(
    const float* __restrict__ last_equ, const bf16x8* __restrict__ packW,
    __bf16* __restrict__ LEp)
{
    __shared__ __attribute__((aligned(16))) __bf16 As[64 * 256];
    const int tid = threadIdx.x, lane = tid & 63, wid = tid >> 6;
    const long row0 = (long)blockIdx.x * 64;
    stage_f32<256>(last_equ, row0, As, tid, (long)N_COARSE * 16 - 1);
    lds_barrier();
    f32x4 acc[4][4] = {};
    mfma_tile(As, packW, 256, wid * 64, 0, acc, lane);
    #pragma unroll
    for (int rt = 0; rt < 4; ++rt) {
        int coarse = (int)(row0 >> 4) + rt;
        #pragma unroll
        for (int ct = 0; ct < 4; ++ct) {
            int cg = wid * 4 + ct;
            bf16x4 v;
            v[0] = (__bf16)acc[rt][ct][0]; v[1] = (__bf16)acc[rt][ct][1];
            v[2] = (__bf16)acc[rt][ct][2]; v[3] = (__bf16)acc[rt][ct][3];
            *(bf16x4*)(LEp + ((size_t)(coarse * 16 + cg) * 64 + lane) * 4) = v;
        }
    }
}

// ---------------------------------------------------------------------------
// Fine fused (R5 one-shot, VGPR-dieted): LE gathers moved AFTER the MFMA
// loop so their 32 destination VGPRs are not live across it. Peak live set
// ~105 VGPR -> 4-5 waves/SIMD (was 3): more cross-block TLP, which is the
// only latency-hiding mechanism that has paid off on this op (R4/R8/R9
// intra-block variants all regressed).
// ---------------------------------------------------------------------------
__global__ __launch_bounds__(256) void k_fine_equ(
    const float* __restrict__ cur_equ, const bf16x8* __restrict__ packW,
    const __bf16* __restrict__ LEp, const int* __restrict__ up,
    __bf16* __restrict__ equ)
{
    __shared__ __attribute__((aligned(16))) __bf16 As[64 * 256];
    const int tid = threadIdx.x, lane = tid & 63, wid = tid >> 6;
    const int n0 = blockIdx.x * 4;
    const long row0 = (long)blockIdx.x * 64;

    int cu[4];
    #pragma unroll
    for (int rt = 0; rt < 4; ++rt) cu[rt] = up[n0 + rt];   // uniform -> s_load

    stage_f32<256>(cur_equ, row0, As, tid, (long)N_FINE * 16 - 1);
    lds_barrier();

    f32x4 acc[4][4] = {};
    mfma_tile(As, packW, 256, wid * 64, 0, acc, lane);

    // LE fragment gathers (post-MFMA: L3-resident table, short tail)
    bf16x4 le[4][4];
    #pragma unroll
    for (int rt = 0; rt < 4; ++rt)
        #pragma unroll
        for (int ct = 0; ct < 4; ++ct)
            le[rt][ct] = *(const bf16x4*)(LEp +
                ((size_t)(cu[rt] * 16 + wid * 4 + ct) * 64 + lane) * 4);

    #pragma unroll
    for (int rt = 0; rt < 4; ++rt) {
        int n = n0 + rt;
        #pragma unroll
        for (int ct = 0; ct < 4; ++ct) {
            float s = acc[rt][ct][0] * (float)le[rt][ct][0]
                    + acc[rt][ct][1] * (float)le[rt][ct][1]
                    + acc[rt][ct][2] * (float)le[rt][ct][2]
                    + acc[rt][ct][3] * (float)le[rt][ct][3];
            s += __shfl_xor(s, 16, 64);   // basis reduce over lane bit 4
            s += __shfl_xor(s, 32, 64);   // basis reduce over lane bit 5
            if (lane < 16)
                equ[(size_t)n * 256 + wid * 64 + ct * 16 + lane] = (__bf16)(s * 0.0625f);
        }
    }
}

// ---------------------------------------------------------------------------
// Output: out = [ last_inv[up] | cur_inv | equ ] @ W_mlp  (K=768). R5 form.
// ---------------------------------------------------------------------------
__global__ __launch_bounds__(512) void k_out(
    const __bf16* __restrict__ li_bf, const float* __restrict__ cur_inv,
    const __bf16* __restrict__ equ, const bf16x8* __restrict__ packW,
    const int* __restrict__ up, float* __restrict__ out)
{
    __shared__ __attribute__((aligned(16))) __bf16 As[64 * 256];
    const int tid = threadIdx.x, lane = tid & 63, wid = tid >> 6;
    const int row0 = blockIdx.x * 64;
    const int c0 = wid * 64;
    const int r0 = tid >> 5, cs = tid & 31;
    f32x4 acc[4][4] = {};

    // seg0: gathered last_inv rows (bf16)
    #pragma unroll
    for (int i = 0; i < 4; ++i) {
        int row = r0 + i * 16;
        int gr = row0 + row; if (gr > N_FINE - 1) gr = N_FINE - 1;
        st_a(As, row, cs, *(const bf16x8*)(li_bf + (size_t)up[gr] * 256 + cs * 8));
    }
    lds_barrier();
    mfma_tile(As, packW, 512, c0, 0, acc, lane);
    lds_barrier();

    // seg1: cur_inv (f32)
    stage_f32<512>(cur_inv, row0, As, tid, N_FINE - 1);
    lds_barrier();
    mfma_tile(As, packW, 512, c0, 8, acc, lane);
    lds_barrier();

    // seg2: equ (bf16)
    #pragma unroll
    for (int i = 0; i < 4; ++i) {
        int row = r0 + i * 16;
        int gr = row0 + row; if (gr > N_FINE - 1) gr = N_FINE - 1;
        st_a(As, row, cs, *(const bf16x8*)(equ + (size_t)gr * 256 + cs * 8));
    }
    lds_barrier();
    mfma_tile(As, packW, 512, c0, 16, acc, lane);

    const int g = lane >> 4, r15 = lane & 15;
    #pragma unroll
    for (int rt = 0; rt < 4; ++rt)
        #pragma unroll
        for (int j = 0; j < 4; ++j) {
            int r = row0 + rt * 16 + g * 4 + j;
            if (r < N_FINE)
                #pragma unroll
                for (int ct = 0; ct < 4; ++ct)
                    out[(size_t)r * 512 + c0 + ct * 16 + r15] = acc[rt][ct][j];
        }
}

extern "C" void kernel_launch(void* const* d_in, const int* in_sizes, int n_in,
                              void* d_out, int out_size, void* d_ws, size_t ws_size,
                              hipStream_t stream) {
    const float* last_inv = (const float*)d_in[0];
    const float* cur_inv  = (const float*)d_in[1];
    const float* last_equ = (const float*)d_in[2];
    const float* cur_equ  = (const float*)d_in[3];
    const int*   up       = (const int*)d_in[4];
    const float* W_le     = (const float*)d_in[5];
    const float* W_ce     = (const float*)d_in[6];
    const float* W_mlp    = (const float*)d_in[7];
    float* out = (float*)d_out;

    // workspace carve-up (~135 MB)
    char* w = (char*)d_ws;
    __bf16* LEp    = (__bf16*)w;  w += (size_t)N_COARSE * 16 * 256 * 2;  // 102.4 MB
    __bf16* equ    = (__bf16*)w;  w += (size_t)N_FINE * 256 * 2;        //  25.6 MB
    __bf16* li_bf  = (__bf16*)w;  w += (size_t)N_COARSE * 256 * 2;      //   6.4 MB
    __bf16* packLE = (__bf16*)w;  w += (size_t)256 * 256 * 2;
    __bf16* packCE = (__bf16*)w;  w += (size_t)256 * 256 * 2;
    __bf16* packM  = (__bf16*)w;  w += (size_t)768 * 512 * 2;

    // merged prep: 256 + 256 + 1536 + 3125 blocks
    k_prep<<<2048 + 3125, 256, 0, stream>>>(
        W_le, W_ce, W_mlp, last_inv, packLE, packCE, packM, li_bf);

    k_coarse_equ<<<N_COARSE * 16 / 64, 256, 0, stream>>>(
        last_equ, (const bf16x8*)packLE, LEp);

    k_fine_equ<<<N_FINE / 4, 256, 0, stream>>>(
        cur_equ, (const bf16x8*)packCE, LEp, up, equ);

    k_out<<<(N_FINE + 63) / 64, 512, 0, stream>>>(
        li_bf, cur_inv, equ, (const bf16x8*)packM, up, out);
}

// Round 13
// 522.330 us; speedup vs baseline: 1.2417x; 1.0587x over previous
//
#include <hip/hip_runtime.h>
#include <hip/hip_bf16.h>

#define N_COARSE 12500
#define N_FINE   50000

typedef __bf16 bf16x8 __attribute__((ext_vector_type(8)));
typedef __bf16 bf16x4 __attribute__((ext_vector_type(4)));
typedef float  f32x4  __attribute__((ext_vector_type(4)));

// ---------------------------------------------------------------------------
// Fragment conventions (v_mfma_f32_16x16x32_bf16), HW-verified:
//   a-frag: lane holds A[row = lane&15][k = (lane>>4)*8 + j]
//   b-frag: lane holds B[k = (lane>>4)*8 + j][col = lane&15]
//   d     : lane holds D[row = (lane>>4)*4 + j][col = lane&15]
// ---------------------------------------------------------------------------

__device__ __forceinline__ bf16x8 cvt8(f32x4 x, f32x4 y) {
    bf16x8 r;
    r[0] = (__bf16)x[0]; r[1] = (__bf16)x[1]; r[2] = (__bf16)x[2]; r[3] = (__bf16)x[3];
    r[4] = (__bf16)y[0]; r[5] = (__bf16)y[1]; r[6] = (__bf16)y[2]; r[7] = (__bf16)y[3];
    return r;
}

// Barrier with LDS-only fence (avoids __syncthreads' vmcnt(0) drain).
__device__ __forceinline__ void lds_barrier() {
    asm volatile("s_waitcnt lgkmcnt(0)" ::: "memory");
    __builtin_amdgcn_s_barrier();
}

// ---- LDS A-tile: [64 rows][256 bf16] = 32 KB, XOR-swizzled ----------------
__device__ __forceinline__ int swz(int row, int byte) { return byte ^ ((row & 7) << 4); }
__device__ __forceinline__ void st_a(__bf16* lds, int row, int cs, bf16x8 v) {
    *(bf16x8*)((char*)lds + swz(row, row * 512 + cs * 16)) = v;
}
__device__ __forceinline__ bf16x8 ld_a(const __bf16* lds, int row, int ka) {
    return *(const bf16x8*)((const char*)lds + swz(row, row * 512 + ka * 2));
}

template<int NT>
__device__ __forceinline__ void stage_f32(const float* __restrict__ A, long row0,
                                          __bf16* lds, int tid, long maxrow) {
    const int r0 = tid >> 5, cs = tid & 31;
    constexpr int RPI = NT / 32;
    #pragma unroll
    for (int i = 0; i < 64 / RPI; ++i) {
        int row = r0 + i * RPI;
        long gr = row0 + row; if (gr > maxrow) gr = maxrow;
        const float* p = A + gr * 256 + cs * 8;
        f32x4 x = *(const f32x4*)p, y = *(const f32x4*)(p + 4);
        st_a(lds, row, cs, cvt8(x, y));
    }
}

// 64x64-per-wave MFMA over one 256-wide K segment, A from LDS, B packed global
__device__ __forceinline__ void mfma_tile(const __bf16* lds, const bf16x8* __restrict__ packB,
                                          int N, int c0, int ksb,
                                          f32x4 (&acc)[4][4], int lane) {
    const int g = lane >> 4, r15 = lane & 15;
    #pragma unroll
    for (int ks = 0; ks < 8; ++ks) {
        bf16x8 a[4];
        #pragma unroll
        for (int rt = 0; rt < 4; ++rt)
            a[rt] = ld_a(lds, rt * 16 + r15, ks * 32 + g * 8);
        const size_t kb = (size_t)((ksb + ks) * 4 + g) * N;
        #pragma unroll
        for (int ct = 0; ct < 4; ++ct) {
            bf16x8 b = packB[kb + c0 + ct * 16 + r15];
            #pragma unroll
            for (int rt = 0; rt < 4; ++rt)
                acc[rt][ct] = __builtin_amdgcn_mfma_f32_16x16x32_bf16(a[rt], b, acc[rt][ct], 0, 0, 0);
        }
    }
}

// ---------------------------------------------------------------------------
// Merged prep: pack W_le / W_ce / W_mlp into MFMA b-frag layout + cvt last_inv
// to bf16. Pack layout: dst[((k>>3)*N + n)*8 + (k&7)] = (bf16)W[k*N + n]
// ---------------------------------------------------------------------------
__global__ __launch_bounds__(256) void k_prep(
    const float* __restrict__ W_le, const float* __restrict__ W_ce,
    const float* __restrict__ W_mlp, const float* __restrict__ last_inv,
    __bf16* __restrict__ packLE, __bf16* __restrict__ packCE,
    __bf16* __restrict__ packM, __bf16* __restrict__ li_bf)
{
    const int b = blockIdx.x, tid = threadIdx.x;
    if (b < 256) {                       // W_le pack (256x256)
        int idx = b * 256 + tid, k = idx >> 8, n = idx & 255;
        packLE[(((size_t)(k >> 3) << 8) + n) * 8 + (k & 7)] = (__bf16)W_le[idx];
    } else if (b < 512) {                // W_ce pack (256x256)
        int idx = (b - 256) * 256 + tid, k = idx >> 8, n = idx & 255;
        packCE[(((size_t)(k >> 3) << 8) + n) * 8 + (k & 7)] = (__bf16)W_ce[idx];
    } else if (b < 2048) {               // W_mlp pack (768x512)
        int idx = (b - 512) * 256 + tid, k = idx >> 9, n = idx & 511;
        packM[(((size_t)(k >> 3) << 9) + n) * 8 + (k & 7)] = (__bf16)W_mlp[idx];
    } else {                             // last_inv f32 -> bf16
        int i = (b - 2048) * 256 + tid;
        f32x4 v = ((const f32x4*)last_inv)[i];
        bf16x4 o;
        o[0] = (__bf16)v[0]; o[1] = (__bf16)v[1]; o[2] = (__bf16)v[2]; o[3] = (__bf16)v[3];
        ((bf16x4*)li_bf)[i] = o;
    }
}

// ---------------------------------------------------------------------------
// Coarse: LE = last_equ @ W_last_equ -> LEp (MFMA D-layout, bf16).
// PERSISTENT grid-stride: same per-tile body as R11, but blocks loop over
// tiles so co-resident blocks drift out of phase (stage of one overlaps
// MFMA of another) instead of convoying through dispatch batches.
// ---------------------------------------------------------------------------
__global__ __launch_bounds__(256) void k_coarse_equ(
    const float* __restrict__ last_equ, const bf16x8* __restrict__ packW,
    __bf16* __restrict__ LEp)
{
    __shared__ __attribute__((aligned(16))) __bf16 As[64 * 256];
    const int tid = threadIdx.x, lane = tid & 63, wid = tid >> 6;
    for (int t = blockIdx.x; t < N_COARSE * 16 / 64; t += gridDim.x) {
        stage_f32<256>(last_equ, (long)t * 64, As, tid, (long)N_COARSE * 16 - 1);
        lds_barrier();
        f32x4 acc[4][4] = {};
        mfma_tile(As, packW, 256, wid * 64, 0, acc, lane);
        #pragma unroll
        for (int rt = 0; rt < 4; ++rt) {
            int coarse = t * 4 + rt;
            #pragma unroll
            for (int ct = 0; ct < 4; ++ct) {
                int cg = wid * 4 + ct;
                bf16x4 v;
                v[0] = (__bf16)acc[rt][ct][0]; v[1] = (__bf16)acc[rt][ct][1];
                v[2] = (__bf16)acc[rt][ct][2]; v[3] = (__bf16)acc[rt][ct][3];
                *(bf16x4*)(LEp + ((size_t)(coarse * 16 + cg) * 64 + lane) * 4) = v;
            }
        }
        lds_barrier();   // As reads done before next iteration overwrites
    }
}

// ---------------------------------------------------------------------------
// Fine fused, PERSISTENT grid-stride; per-tile body identical to R11
// (stage -> lgkm barrier -> MFMA -> post-MFMA LE gathers -> mean -> store).
// ---------------------------------------------------------------------------
__global__ __launch_bounds__(256) void k_fine_equ(
    const float* __restrict__ cur_equ, const bf16x8* __restrict__ packW,
    const __bf16* __restrict__ LEp, const int* __restrict__ up,
    __bf16* __restrict__ equ)
{
    __shared__ __attribute__((aligned(16))) __bf16 As[64 * 256];
    const int tid = threadIdx.x, lane = tid & 63, wid = tid >> 6;
    for (int t = blockIdx.x; t < N_FINE / 4; t += gridDim.x) {
        const int n0 = t * 4;
        int cu[4];
        #pragma unroll
        for (int rt = 0; rt < 4; ++rt) cu[rt] = up[n0 + rt];   // uniform -> s_load

        stage_f32<256>(cur_equ, (long)t * 64, As, tid, (long)N_FINE * 16 - 1);
        lds_barrier();

        f32x4 acc[4][4] = {};
        mfma_tile(As, packW, 256, wid * 64, 0, acc, lane);

        // LE fragment gathers post-MFMA (VGPRs not live across the GEMM)
        bf16x4 le[4][4];
        #pragma unroll
        for (int rt = 0; rt < 4; ++rt)
            #pragma unroll
            for (int ct = 0; ct < 4; ++ct)
                le[rt][ct] = *(const bf16x4*)(LEp +
                    ((size_t)(cu[rt] * 16 + wid * 4 + ct) * 64 + lane) * 4);

        #pragma unroll
        for (int rt = 0; rt < 4; ++rt) {
            int n = n0 + rt;
            #pragma unroll
            for (int ct = 0; ct < 4; ++ct) {
                float s = acc[rt][ct][0] * (float)le[rt][ct][0]
                        + acc[rt][ct][1] * (float)le[rt][ct][1]
                        + acc[rt][ct][2] * (float)le[rt][ct][2]
                        + acc[rt][ct][3] * (float)le[rt][ct][3];
                s += __shfl_xor(s, 16, 64);   // basis reduce over lane bit 4
                s += __shfl_xor(s, 32, 64);   // basis reduce over lane bit 5
                if (lane < 16)
                    equ[(size_t)n * 256 + wid * 64 + ct * 16 + lane] =
                        (__bf16)(s * 0.0625f);
            }
        }
        lds_barrier();   // As reads done before next iteration overwrites
    }
}

// ---------------------------------------------------------------------------
// Output: out = [ last_inv[up] | cur_inv | equ ] @ W_mlp  (K=768). R5/R11 form.
// ---------------------------------------------------------------------------
__global__ __launch_bounds__(512) void k_out(
    const __bf16* __restrict__ li_bf, const float* __restrict__ cur_inv,
    const __bf16* __restrict__ equ, const bf16x8* __restrict__ packW,
    const int* __restrict__ up, float* __restrict__ out)
{
    __shared__ __attribute__((aligned(16))) __bf16 As[64 * 256];
    const int tid = threadIdx.x, lane = tid & 63, wid = tid >> 6;
    const int row0 = blockIdx.x * 64;
    const int c0 = wid * 64;
    const int r0 = tid >> 5, cs = tid & 31;
    f32x4 acc[4][4] = {};

    // seg0: gathered last_inv rows (bf16)
    #pragma unroll
    for (int i = 0; i < 4; ++i) {
        int row = r0 + i * 16;
        int gr = row0 + row; if (gr > N_FINE - 1) gr = N_FINE - 1;
        st_a(As, row, cs, *(const bf16x8*)(li_bf + (size_t)up[gr] * 256 + cs * 8));
    }
    lds_barrier();
    mfma_tile(As, packW, 512, c0, 0, acc, lane);
    lds_barrier();

    // seg1: cur_inv (f32)
    stage_f32<512>(cur_inv, row0, As, tid, N_FINE - 1);
    lds_barrier();
    mfma_tile(As, packW, 512, c0, 8, acc, lane);
    lds_barrier();

    // seg2: equ (bf16)
    #pragma unroll
    for (int i = 0; i < 4; ++i) {
        int row = r0 + i * 16;
        int gr = row0 + row; if (gr > N_FINE - 1) gr = N_FINE - 1;
        st_a(As, row, cs, *(const bf16x8*)(equ + (size_t)gr * 256 + cs * 8));
    }
    lds_barrier();
    mfma_tile(As, packW, 512, c0, 16, acc, lane);

    const int g = lane >> 4, r15 = lane & 15;
    #pragma unroll
    for (int rt = 0; rt < 4; ++rt)
        #pragma unroll
        for (int j = 0; j < 4; ++j) {
            int r = row0 + rt * 16 + g * 4 + j;
            if (r < N_FINE)
                #pragma unroll
                for (int ct = 0; ct < 4; ++ct)
                    out[(size_t)r * 512 + c0 + ct * 16 + r15] = acc[rt][ct][j];
        }
}

extern "C" void kernel_launch(void* const* d_in, const int* in_sizes, int n_in,
                              void* d_out, int out_size, void* d_ws, size_t ws_size,
                              hipStream_t stream) {
    const float* last_inv = (const float*)d_in[0];
    const float* cur_inv  = (const float*)d_in[1];
    const float* last_equ = (const float*)d_in[2];
    const float* cur_equ  = (const float*)d_in[3];
    const int*   up       = (const int*)d_in[4];
    const float* W_le     = (const float*)d_in[5];
    const float* W_ce     = (const float*)d_in[6];
    const float* W_mlp    = (const float*)d_in[7];
    float* out = (float*)d_out;

    // workspace carve-up (~135 MB)
    char* w = (char*)d_ws;
    __bf16* LEp    = (__bf16*)w;  w += (size_t)N_COARSE * 16 * 256 * 2;  // 102.4 MB
    __bf16* equ    = (__bf16*)w;  w += (size_t)N_FINE * 256 * 2;        //  25.6 MB
    __bf16* li_bf  = (__bf16*)w;  w += (size_t)N_COARSE * 256 * 2;      //   6.4 MB
    __bf16* packLE = (__bf16*)w;  w += (size_t)256 * 256 * 2;
    __bf16* packCE = (__bf16*)w;  w += (size_t)256 * 256 * 2;
    __bf16* packM  = (__bf16*)w;  w += (size_t)768 * 512 * 2;

    k_prep<<<2048 + 3125, 256, 0, stream>>>(
        W_le, W_ce, W_mlp, last_inv, packLE, packCE, packM, li_bf);

    // persistent grids: 5 blocks/CU x 256 CUs (32 KB LDS, ~100 VGPR)
    k_coarse_equ<<<1280, 256, 0, stream>>>(
        last_equ, (const bf16x8*)packLE, LEp);

    k_fine_equ<<<1280, 256, 0, stream>>>(
        cur_equ, (const bf16x8*)packCE, LEp, up, equ);

    k_out<<<(N_FINE + 63) / 64, 512, 0, stream>>>(
        li_bf, cur_inv, equ, (const bf16x8*)packM, up, out);
}